// Round 2
// baseline (505.661 us; speedup 1.0000x reference)
//
#include <hip/hip_runtime.h>

#define BATCH 32768
#define NVEC  4096
#define EDIM  256
#define KNN   20

#define BM 64            // samples per block
#define NTHREADS 256     // 4 waves; __launch_bounds__(256,2) -> 256-reg cap, no spills
#define RPW 1024         // rows scanned per wave (4 waves x 1024 = all 4096)
#define NCHUNK 16        // RPW / 64
#define XPITCH 264       // x-LDS row pitch in ushorts (256+8)
#define SPITCH 17        // stats pitch: 16 contributors + 1 pad
#define MARGIN 2.0f      // > 2 * worst-case bf16 dot error (~0.7)
#define FINF   3.4e38f

typedef short          s16x8 __attribute__((ext_vector_type(8)));
typedef unsigned short u16x8 __attribute__((ext_vector_type(8)));
typedef float          f32x4 __attribute__((ext_vector_type(4)));

__device__ __forceinline__ unsigned short f2bf(float f) {
  unsigned int u = __float_as_uint(f);
  u += 0x7fffu + ((u >> 16) & 1u);   // RNE; inputs finite
  return (unsigned short)(u >> 16);
}

// monotone float<->uint encoding: order-preserving over all finite floats
__device__ __forceinline__ unsigned int fenc(float f) {
  unsigned int u = __float_as_uint(f);
  return (u & 0x80000000u) ? ~u : (u | 0x80000000u);
}

// fp32 k-ascending dot — EXACT source pattern of the passing kernel
// (same compiler contraction => same rounding class as the reference).
__device__ __forceinline__ float dot_np(const float4* __restrict__ xq,
                                        const float4* __restrict__ wq) {
  float d = 0.f;
  for (int k = 0; k < EDIM / 4; k++) {
    float4 a4 = xq[k], b4 = wq[k];
    d += a4.x * b4.x;
    d += a4.y * b4.y;
    d += a4.z * b4.z;
    d += a4.w * b4.w;
  }
  return d;
}

__global__ __launch_bounds__(256)
void k_convert_w(const float* __restrict__ W, unsigned short* __restrict__ Wb) {
  int i = blockIdx.x * 256 + threadIdx.x;   // 262144 float4 groups
  float4 v = ((const float4*)W)[i];
  ushort4 o; o.x = f2bf(v.x); o.y = f2bf(v.y); o.z = f2bf(v.z); o.w = f2bf(v.w);
  ((ushort4*)Wb)[i] = o;
}

// per-code weighted-window output table O[4096][256]
__global__ __launch_bounds__(256)
void k_code_out(const float* __restrict__ W, float* __restrict__ Otab) {
  const int lane = threadIdx.x & 63;
  const int code = blockIdx.x * 4 + (threadIdx.x >> 6);
  float w = 0.f;
  if (lane < 41) {
    int d = lane - KNN;
    int idx = code + d;
    bool left  = (code - KNN) < 0;
    bool valid = (idx >= 0) && (idx < NVEC) && (!left || (d < KNN));
    w = valid ? expf(-0.5f * (float)(d * d)) : 0.f;
  }
  float ssum = w;
  #pragma unroll
  for (int off = 32; off >= 1; off >>= 1) ssum += __shfl_xor(ssum, off);
  float inv = 1.f / ssum;

  float4 acc = {0.f, 0.f, 0.f, 0.f};
  #pragma unroll
  for (int d = 0; d < 41; d++) {
    float wd = __shfl(w, d);
    int idx = code + d - KNN;
    idx = idx < 0 ? 0 : (idx >= NVEC ? NVEC - 1 : idx);
    float4 wr = *(const float4*)(W + (size_t)idx * EDIM + lane * 4);
    acc.x += wd * wr.x; acc.y += wd * wr.y;
    acc.z += wd * wr.z; acc.w += wd * wr.w;
  }
  acc.x *= inv; acc.y *= inv; acc.z *= inv; acc.w *= inv;
  *(float4*)(Otab + (size_t)code * EDIM + lane * 4) = acc;
}

// fused GEMM + argmin + refine + output.
// Hot loop: MFMA + ds_read + 2-deep global prefetch + branchless register
// (min1,row,min2) tracking. NO shfl/LDS/atomic/branch per chunk.
__global__ __launch_bounds__(NTHREADS, 2)
void k_all(const float* __restrict__ x, const float* __restrict__ W,
           const unsigned short* __restrict__ Wb,
           const float* __restrict__ Otab, float* __restrict__ out) {
  __shared__ unsigned short xs[BM * XPITCH];   // 33792 B
  __shared__ float m1s[BM * SPITCH];           // 4352 B
  __shared__ float m2s[BM * SPITCH];           // 4352 B
  __shared__ int   rws[BM * SPITCH];           // 4352 B
  __shared__ int   sbad;

  const int t    = threadIdx.x;
  const int lane = t & 63;
  const int wv   = t >> 6;        // 0..3
  const int lm   = lane & 15;
  const int lq   = lane >> 4;
  const int m0   = blockIdx.x * BM;

  if (t == 0) sbad = 0;

  // ---- stage x tile: fp32 global -> RNE bf16 -> padded LDS ----
  {
    const int r = t >> 2, q = t & 3;
    const float* xp = x + (size_t)(m0 + r) * EDIM + q * 64;
    unsigned short* dst = xs + r * XPITCH + q * 64;
    #pragma unroll
    for (int u = 0; u < 8; u++) {
      float4 v0 = *(const float4*)(xp + u * 8);
      float4 v1 = *(const float4*)(xp + u * 8 + 4);
      u16x8 uu;
      uu[0] = f2bf(v0.x); uu[1] = f2bf(v0.y); uu[2] = f2bf(v0.z); uu[3] = f2bf(v0.w);
      uu[4] = f2bf(v1.x); uu[5] = f2bf(v1.y); uu[6] = f2bf(v1.z); uu[7] = f2bf(v1.w);
      *(u16x8*)(dst + u * 8) = uu;
    }
  }

  // ---- W base pointers (one per i-group) + 2-stage prologue prefetch ----
  const unsigned short* wA = Wb + (size_t)(wv * RPW + lm) * EDIM + lq * 8;
  const unsigned short* wB = wA + 16 * EDIM;
  const unsigned short* wC = wA + 32 * EDIM;
  const unsigned short* wD = wA + 48 * EDIM;
  s16x8 a[4][4];   // 4 rotating stages x 4 i-frags (static idx only)
  a[0][0] = *(const s16x8*)(wA);      a[0][1] = *(const s16x8*)(wB);
  a[0][2] = *(const s16x8*)(wC);      a[0][3] = *(const s16x8*)(wD);
  a[1][0] = *(const s16x8*)(wA + 32); a[1][1] = *(const s16x8*)(wB + 32);
  a[1][2] = *(const s16x8*)(wC + 32); a[1][3] = *(const s16x8*)(wD + 32);

  __syncthreads();   // the only pre-refine barrier

  const f32x4 fz = {0.f, 0.f, 0.f, 0.f};
  float m1[4] = {FINF, FINF, FINF, FINF};
  float m2[4] = {FINF, FINF, FINF, FINF};
  int   r1[4] = {0, 0, 0, 0};
  int   rbl   = wv * RPW + lq * 4;   // row base for this lane's (i=0,r=0)

  for (int nc = 0; nc < NCHUNK; nc++) {
    f32x4 acc[4][4];
    #pragma unroll
    for (int i = 0; i < 4; i++)
      #pragma unroll
      for (int j = 0; j < 4; j++) acc[i][j] = fz;

    #pragma unroll
    for (int s = 0; s < 8; s++) {
      // issue distance-2 prefetch into stage (s+2)&3
      if (s < 6) {
        const int off = (s + 2) * 32;
        a[(s + 2) & 3][0] = *(const s16x8*)(wA + off);
        a[(s + 2) & 3][1] = *(const s16x8*)(wB + off);
        a[(s + 2) & 3][2] = *(const s16x8*)(wC + off);
        a[(s + 2) & 3][3] = *(const s16x8*)(wD + off);
        if (s == 5) {   // advance to next chunk (64 rows) for s=6,7 prefetches
          wA += 64 * EDIM; wB += 64 * EDIM; wC += 64 * EDIM; wD += 64 * EDIM;
        }
      } else {
        // next chunk, cols 0/1. Last chunk over-reads <=32KB into Otab: harmless.
        const int off = (s - 6) * 32;
        a[(s + 2) & 3][0] = *(const s16x8*)(wA + off);
        a[(s + 2) & 3][1] = *(const s16x8*)(wB + off);
        a[(s + 2) & 3][2] = *(const s16x8*)(wC + off);
        a[(s + 2) & 3][3] = *(const s16x8*)(wD + off);
      }
      // consume stage s&3
      #pragma unroll
      for (int j = 0; j < 4; j++) {
        s16x8 bj = *(const s16x8*)(xs + (j * 16 + lm) * XPITCH + s * 32 + lq * 8);
        #pragma unroll
        for (int i = 0; i < 4; i++)
          acc[i][j] = __builtin_amdgcn_mfma_f32_16x16x32_bf16(a[s & 3][i], bj, acc[i][j], 0, 0, 0);
      }
    }

    // ---- layout self-check (chunk 0): exact dot vs acc[0][0][0] ----
    if (nc == 0) {
      float ex = dot_np((const float4*)(x + (size_t)(m0 + lm) * EDIM),
                        (const float4*)(W + (size_t)(wv * RPW + lq * 4) * EDIM));
      if (fabsf(ex - acc[0][0][0]) > 2.0f) sbad = 1;
    }

    // ---- branchless per-lane (min1,row,min2) update, ascending row order ----
    #pragma unroll
    for (int j = 0; j < 4; j++) {
      #pragma unroll
      for (int i = 0; i < 4; i++) {
        #pragma unroll
        for (int r = 0; r < 4; r++) {
          float v = acc[i][j][r];
          m2[j] = fminf(m2[j], fmaxf(m1[j], v));   // uses old m1
          bool lt = v < m1[j];                     // tie -> keep earlier row
          int rowc = rbl + i * 16 + r;
          r1[j] = lt ? rowc : r1[j];
          m1[j] = fminf(m1[j], v);
        }
      }
    }
    rbl += 64;
  }

  // ---- publish per-contributor stats, one time ----
  {
    const int c = wv * 4 + lq;
    #pragma unroll
    for (int j = 0; j < 4; j++) {
      const int sl = j * 16 + lm;
      m1s[sl * SPITCH + c] = m1[j];
      m2s[sl * SPITCH + c] = m2[j];
      rws[sl * SPITCH + c] = r1[j];
    }
  }
  __syncthreads();

  // ---- refine + output: np-order fp32 dots; min value, tie -> smaller idx ----
  const bool bad = (sbad != 0);
  for (int u = 0; u < 16; u++) {
    const int sl = wv * 16 + u;
    const int b  = m0 + sl;
    const float4* xq = (const float4*)(x + (size_t)b * EDIM);
    float m1c = FINF, m2c = FINF; int rc = 0;
    if (lane < 16) {
      m1c = m1s[sl * SPITCH + lane];
      m2c = m2s[sl * SPITCH + lane];
      rc  = rws[sl * SPITCH + lane];
    }
    // min over 16 contributors (4-level butterfly within 16-lane groups)
    float gm = m1c;
    gm = fminf(gm, __shfl_xor(gm, 1));
    gm = fminf(gm, __shfl_xor(gm, 2));
    gm = fminf(gm, __shfl_xor(gm, 4));
    gm = fminf(gm, __shfl_xor(gm, 8));

    unsigned long long bestkey = 0xFFFFFFFFFFFFFFFFull;
    if (!bad) {
      const float th = gm + MARGIN;   // valid on lanes<16 (only used there)
      if (lane < 16 && m1c <= th) {
        float d = dot_np(xq, (const float4*)(W + (size_t)rc * EDIM));
        bestkey = ((unsigned long long)fenc(d) << 32) | (unsigned)rc;
      }
      // dirty contributors may hide extra near-min rows -> exact rescan of
      // that contributor's 256 rows (4 per lane), rare (~2% of samples)
      unsigned long long db = __ballot(lane < 16 && m2c <= th);
      while (db) {
        int c = __builtin_ctzll(db); db &= db - 1;
        const int base = (c >> 2) * RPW + (c & 3) * 4;
        #pragma unroll
        for (int tt = 0; tt < 4; tt++) {
          int n = lane * 4 + tt;
          int row = base + (n >> 4) * 64 + ((n >> 2) & 3) * 16 + (n & 3);
          float d = dot_np(xq, (const float4*)(W + (size_t)row * EDIM));
          unsigned long long key = ((unsigned long long)fenc(d) << 32) | (unsigned)row;
          if (key < bestkey) bestkey = key;
        }
      }
    } else {
      // fallback (layout-bad): full scan, np-order fp32
      for (int n = lane; n < NVEC; n += 64) {
        float d = dot_np(xq, (const float4*)(W + (size_t)n * EDIM));
        unsigned long long key = ((unsigned long long)fenc(d) << 32) | (unsigned)n;
        if (key < bestkey) bestkey = key;
      }
    }
    #pragma unroll
    for (int off = 32; off >= 1; off >>= 1) {
      unsigned long long o = __shfl_xor(bestkey, off);
      if (o < bestkey) bestkey = o;
    }
    // all lanes hold the winning key -> gather Otab row, write out
    const int id = (int)(unsigned int)(bestkey & 0xFFFFFFFFull);
    float4 v = *(const float4*)(Otab + (size_t)id * EDIM + lane * 4);
    *(float4*)(out + (size_t)b * EDIM + lane * 4) = v;
  }
}

extern "C" void kernel_launch(void* const* d_in, const int* in_sizes, int n_in,
                              void* d_out, int out_size, void* d_ws, size_t ws_size,
                              hipStream_t stream) {
  const float* x = (const float*)d_in[0];   // [32768,256] fp32
  const float* W = (const float*)d_in[1];   // [4096,256]  fp32
  float* out = (float*)d_out;

  char* ws = (char*)d_ws;
  unsigned short* Wb = (unsigned short*)ws;                        // 2 MB
  float* Otab = (float*)(ws + (size_t)NVEC * EDIM * 2);            // 4 MB

  k_convert_w<<<NVEC * EDIM / 4 / 256, 256, 0, stream>>>(W, Wb);
  k_code_out<<<NVEC / 4, 256, 0, stream>>>(W, Otab);
  k_all<<<BATCH / BM, NTHREADS, 0, stream>>>(x, W, Wb, Otab, out);
}

// Round 3
// 465.305 us; speedup vs baseline: 1.0867x; 1.0867x over previous
//
#include <hip/hip_runtime.h>

#define BATCH 32768
#define NVEC  4096
#define EDIM  256
#define KNN   20

#define TS 128               // samples per gemm block
#define TC 128               // codes per gemm block
#define NCT (NVEC/TC)        // 32 code tiles
#define NST (BATCH/TS)       // 256 sample tiles
#define GGRID (NST*NCT)      // 8192 blocks
#define MARGIN 2.0f          // > 2 * worst-case bf16 dot error (~0.8)
#define FINF   3.4e38f

typedef short          s16x8 __attribute__((ext_vector_type(8)));
typedef unsigned short u16x8 __attribute__((ext_vector_type(8)));
typedef float          f32x4 __attribute__((ext_vector_type(4)));

__device__ __forceinline__ unsigned short f2bf(float f) {
  unsigned int u = __float_as_uint(f);
  u += 0x7fffu + ((u >> 16) & 1u);   // RNE; inputs finite
  return (unsigned short)(u >> 16);
}

// monotone float->uint encoding: order-preserving over all finite floats
__device__ __forceinline__ unsigned int fenc(float f) {
  unsigned int u = __float_as_uint(f);
  return (u & 0x80000000u) ? ~u : (u | 0x80000000u);
}

// fp32 k-ascending dot — EXACT source pattern of the passing kernels
// (same compiler contraction => same rounding class as the reference).
__device__ __forceinline__ float dot_np(const float4* __restrict__ xq,
                                        const float4* __restrict__ wq) {
  float d = 0.f;
  for (int k = 0; k < EDIM / 4; k++) {
    float4 a4 = xq[k], b4 = wq[k];
    d += a4.x * b4.x;
    d += a4.y * b4.y;
    d += a4.z * b4.z;
    d += a4.w * b4.w;
  }
  return d;
}

__device__ __forceinline__ void gload16(const unsigned short* g, unsigned short* l) {
  __builtin_amdgcn_global_load_lds(
      (const __attribute__((address_space(1))) unsigned int*)g,
      (__attribute__((address_space(3))) unsigned int*)l, 16, 0, 0);
}

__global__ __launch_bounds__(256)
void k_convert_w(const float* __restrict__ W, unsigned short* __restrict__ Wb,
                 int* __restrict__ flag) {
  if (blockIdx.x == 0 && threadIdx.x == 0) *flag = 0;
  int i = blockIdx.x * 256 + threadIdx.x;   // 262144 float4 groups
  float4 v = ((const float4*)W)[i];
  ushort4 o; o.x = f2bf(v.x); o.y = f2bf(v.y); o.z = f2bf(v.z); o.w = f2bf(v.w);
  ((ushort4*)Wb)[i] = o;
}

// per-code weighted-window output table O[4096][256]
__global__ __launch_bounds__(256)
void k_code_out(const float* __restrict__ W, float* __restrict__ Otab) {
  const int lane = threadIdx.x & 63;
  const int code = blockIdx.x * 4 + (threadIdx.x >> 6);
  float w = 0.f;
  if (lane < 41) {
    int d = lane - KNN;
    int idx = code + d;
    bool left  = (code - KNN) < 0;
    bool valid = (idx >= 0) && (idx < NVEC) && (!left || (d < KNN));
    w = valid ? expf(-0.5f * (float)(d * d)) : 0.f;
  }
  float ssum = w;
  #pragma unroll
  for (int off = 32; off >= 1; off >>= 1) ssum += __shfl_xor(ssum, off);
  float inv = 1.f / ssum;

  float4 acc = {0.f, 0.f, 0.f, 0.f};
  #pragma unroll
  for (int d = 0; d < 41; d++) {
    float wd = __shfl(w, d);
    int idx = code + d - KNN;
    idx = idx < 0 ? 0 : (idx >= NVEC ? NVEC - 1 : idx);
    float4 wr = *(const float4*)(W + (size_t)idx * EDIM + lane * 4);
    acc.x += wd * wr.x; acc.y += wd * wr.y;
    acc.z += wd * wr.z; acc.w += wd * wr.w;
  }
  acc.x *= inv; acc.y *= inv; acc.z *= inv; acc.w *= inv;
  *(float4*)(Otab + (size_t)code * EDIM + lane * 4) = acc;
}

// ---- tiled GEMM + per-tile argmin stats ----
// 128x128 tile, K=256 in 4 quarters of 64. W staged async via global_load_lds
// (double-buffered); x reg-staged f32->bf16 per quarter (loads issued before
// compute, ds_write after). LDS stored in fragment-read order so every
// ds_read_b128 is linear in lane (conflict-free) and gload's linear-dest
// constraint is satisfied with no swizzle.
//
// W-LDS  : [buf][g(8)*2+s(2)][1KB: chunk = lq*16+lm, 16B each]
// x-LDS  : [(kq&1)*2+s][G(8)][1KB: chunk = lq*16+lm]
// frag (c=g*16+lm, kbytes = kq*128+s*64+lq*16)  <-> chunk lane*16B. 64KB total.
#define STAGE_W(kq_, buf_) { \
  _Pragma("unroll") \
  for (int n_ = 0; n_ < 4; n_++) { \
    const int blk_ = wv * 4 + n_; \
    const int c_ = blk_ * 64 + lane; \
    const int lm_ = c_ & 15, lq_ = (c_ >> 4) & 3, s_ = (c_ >> 6) & 1, g_ = (c_ >> 7) & 7; \
    gload16(wt + (size_t)(g_ * 16 + lm_) * EDIM + (kq_) * 64 + s_ * 32 + lq_ * 8, \
            wls + (size_t)(buf_) * 8192 + blk_ * 512); \
  } }

#define XLOAD(kq_) { \
  const float* p_ = xt + (size_t)xr * EDIM + (kq_) * 64 + xh * 32; \
  _Pragma("unroll") \
  for (int u_ = 0; u_ < 8; u_++) xv[u_] = ((const float4*)p_)[u_]; }

#define XWRITE(kq_) { \
  _Pragma("unroll") \
  for (int u2_ = 0; u2_ < 4; u2_++) { \
    float4 a_ = xv[u2_ * 2], b_ = xv[u2_ * 2 + 1]; \
    u16x8 o_; \
    o_[0] = f2bf(a_.x); o_[1] = f2bf(a_.y); o_[2] = f2bf(a_.z); o_[3] = f2bf(a_.w); \
    o_[4] = f2bf(b_.x); o_[5] = f2bf(b_.y); o_[6] = f2bf(b_.z); o_[7] = f2bf(b_.w); \
    *(u16x8*)(xls + ((((kq_) & 1) * 2 + xh) * 8 + (xr >> 4)) * 512 + (u2_ * 16 + (xr & 15)) * 8) = o_; \
  } }

__global__ __launch_bounds__(256, 2)
void k_gemm(const float* __restrict__ x, const float* __restrict__ W,
            const unsigned short* __restrict__ Wb,
            float4* __restrict__ part, int* __restrict__ flag) {
  __shared__ unsigned short xls[2 * 2 * 8 * 512];   // 32 KB
  __shared__ unsigned short wls[2 * 8 * 2 * 512];   // 32 KB

  const int t = threadIdx.x, lane = t & 63, wv = t >> 6;
  const int lm = lane & 15, lq = lane >> 4;
  const int wm = wv >> 1, wn = wv & 1;

  const int bid = blockIdx.x;
  const int swz = (bid & 7) * (GGRID / 8) + (bid >> 3);  // XCD-contiguous
  const int st = swz >> 5, ct = swz & 31;

  const float* xt = x + (size_t)st * TS * EDIM;
  const unsigned short* wt = Wb + (size_t)ct * TC * EDIM;
  const int xr = t >> 1, xh = t & 1;

  f32x4 acc[4][4];
  #pragma unroll
  for (int i = 0; i < 4; i++)
    #pragma unroll
    for (int j = 0; j < 4; j++) acc[i][j] = (f32x4){0.f, 0.f, 0.f, 0.f};

  float4 xv[8];

  // prologue: async W q0 + reg-staged x q0
  STAGE_W(0, 0)
  XLOAD(0)
  XWRITE(0)
  __syncthreads();

  #pragma unroll
  for (int kq = 0; kq < 4; kq++) {
    const int buf = kq & 1;
    if (kq < 3) {
      STAGE_W(kq + 1, buf ^ 1)   // async into other W buffer
      XLOAD(kq + 1)              // x loads in flight during compute (T14)
    }
    #pragma unroll
    for (int s = 0; s < 2; s++) {
      s16x8 av[4], bv[4];
      #pragma unroll
      for (int i = 0; i < 4; i++)
        av[i] = *(const s16x8*)(wls + (size_t)buf * 8192 + ((wn * 4 + i) * 2 + s) * 512 + lane * 8);
      #pragma unroll
      for (int j = 0; j < 4; j++)
        bv[j] = *(const s16x8*)(xls + ((buf * 2 + s) * 8 + (wm * 4 + j)) * 512 + lane * 8);
      #pragma unroll
      for (int i = 0; i < 4; i++)
        #pragma unroll
        for (int j = 0; j < 4; j++)
          acc[i][j] = __builtin_amdgcn_mfma_f32_16x16x32_bf16(av[i], bv[j], acc[i][j], 0, 0, 0);
    }
    if (kq < 3) XWRITE(kq + 1)
    __syncthreads();   // drains gload queue; all reads of this iter done
  }

  // ---- layout self-check (one block, all wave quadrants, transpose-detecting) ----
  if (swz == 0) {
    float ex = dot_np((const float4*)(x + (size_t)(wm * 64 + lm) * EDIM),
                      (const float4*)(W + (size_t)(wn * 64 + lq * 4 + 1) * EDIM));
    if (fabsf(ex - acc[0][0][1]) > 2.0f) *flag = 1;
  }

  // ---- per-sample (m1,row,m2) over this wave's 64 codes, ascending row ----
  float m1a[4], m2a[4]; int r1a[4];
  #pragma unroll
  for (int j = 0; j < 4; j++) {
    float m1 = FINF, m2 = FINF; int r1 = 0;
    #pragma unroll
    for (int i = 0; i < 4; i++)
      #pragma unroll
      for (int r = 0; r < 4; r++) {
        float v = acc[i][j][r];
        m2 = fminf(m2, fmaxf(m1, v));
        bool lt = v < m1;
        r1 = lt ? (ct * TC + wn * 64 + i * 16 + lq * 4 + r) : r1;
        m1 = fminf(m1, v);
      }
    #pragma unroll
    for (int off = 16; off <= 32; off <<= 1) {
      float om1 = __shfl_xor(m1, off);
      float om2 = __shfl_xor(m2, off);
      int   or1 = __shfl_xor(r1, off);
      float nm2 = fminf(fminf(fmaxf(m1, om1), m2), om2);
      bool tk = (om1 < m1) || (om1 == m1 && or1 < r1);
      m1 = tk ? om1 : m1; r1 = tk ? or1 : r1; m2 = nm2;
    }
    m1a[j] = m1; m2a[j] = m2; r1a[j] = r1;
  }

  // merge wn halves via LDS (alias wls: all reads done), write partials
  float4* smrg = (float4*)wls;
  if (wn == 1 && lq == 0) {
    #pragma unroll
    for (int j = 0; j < 4; j++)
      smrg[wm * 64 + j * 16 + lm] =
          make_float4(m1a[j], m2a[j], __int_as_float(r1a[j]), 0.f);
  }
  __syncthreads();
  if (wn == 0 && lq == 0) {
    #pragma unroll
    for (int j = 0; j < 4; j++) {
      const int srow = wm * 64 + j * 16 + lm;
      float4 o = smrg[srow];
      float m1 = m1a[j], m2 = m2a[j]; int r1 = r1a[j];
      float nm2 = fminf(fminf(fmaxf(m1, o.x), m2), o.y);
      bool tk = (o.x < m1);   // wn1 rows always larger: tie keeps wn0 (smaller idx)
      m1 = tk ? o.x : m1;
      r1 = tk ? __float_as_int(o.z) : r1;
      part[(size_t)(st * TS + srow) * NCT + ct] =
          make_float4(m1, nm2, __int_as_float(r1), 0.f);
    }
  }
}

// ---- per-sample reduce + exact-dot refine + output ----
__global__ __launch_bounds__(512)
void k_pick(const float* __restrict__ x, const float* __restrict__ W,
            const float4* __restrict__ part, const float* __restrict__ Otab,
            const int* __restrict__ flag, float* __restrict__ out) {
  const int lane = threadIdx.x & 63, wv = threadIdx.x >> 6;
  const int b = blockIdx.x * 8 + wv;
  const int c = lane & 31;

  float4 p = part[(size_t)b * NCT + c];
  float m1 = p.x, m2 = p.y;
  int   r1 = __float_as_int(p.z);

  float gm = m1;
  #pragma unroll
  for (int off = 32; off >= 1; off >>= 1) gm = fminf(gm, __shfl_xor(gm, off));
  const float th = gm + MARGIN;

  const float4* xq = (const float4*)(x + (size_t)b * EDIM);
  unsigned long long best = 0xFFFFFFFFFFFFFFFFull;

  if (*flag == 0) {
    if (lane < 32 && m1 <= th) {
      float d = dot_np(xq, (const float4*)(W + (size_t)r1 * EDIM));
      best = ((unsigned long long)fenc(d) << 32) | (unsigned)r1;
    }
    // dirty contributors may hide extra near-min rows -> exact rescan (rare)
    unsigned long long db = __ballot(lane < 32 && m2 <= th);
    while (db) {
      int cc = __builtin_ctzll(db); db &= db - 1;
      const int base = cc * TC;
      #pragma unroll
      for (int tt = 0; tt < 2; tt++) {
        int row = base + lane * 2 + tt;
        float d = dot_np(xq, (const float4*)(W + (size_t)row * EDIM));
        unsigned long long key = ((unsigned long long)fenc(d) << 32) | (unsigned)row;
        if (key < best) best = key;
      }
    }
  } else {
    // layout-bad fallback: full np-order scan
    for (int n = lane; n < NVEC; n += 64) {
      float d = dot_np(xq, (const float4*)(W + (size_t)n * EDIM));
      unsigned long long key = ((unsigned long long)fenc(d) << 32) | (unsigned)n;
      if (key < best) best = key;
    }
  }

  #pragma unroll
  for (int off = 32; off >= 1; off >>= 1) {
    unsigned long long o = __shfl_xor(best, off);
    if (o < best) best = o;
  }
  const int id = (int)(unsigned int)(best & 0xFFFFFFFFull);
  float4 v = *(const float4*)(Otab + (size_t)id * EDIM + lane * 4);
  *(float4*)(out + (size_t)b * EDIM + lane * 4) = v;
}

extern "C" void kernel_launch(void* const* d_in, const int* in_sizes, int n_in,
                              void* d_out, int out_size, void* d_ws, size_t ws_size,
                              hipStream_t stream) {
  const float* x = (const float*)d_in[0];   // [32768,256] fp32
  const float* W = (const float*)d_in[1];   // [4096,256]  fp32
  float* out = (float*)d_out;

  char* ws = (char*)d_ws;
  unsigned short* Wb = (unsigned short*)ws;                 // 2 MB
  float* Otab  = (float*)(ws + (2u << 20));                 // 4 MB
  float4* part = (float4*)(ws + (6u << 20));                // 16 MB (32768 x 32 x 16B)
  int* flag    = (int*)(ws + (22u << 20));                  // 4 B

  k_convert_w<<<1024, 256, 0, stream>>>(W, Wb, flag);
  k_code_out<<<1024, 256, 0, stream>>>(W, Otab);
  k_gemm<<<GGRID, 256, 0, stream>>>(x, W, Wb, part, flag);
  k_pick<<<BATCH / 8, 512, 0, stream>>>(x, W, part, Otab, flag, out);
}

// Round 4
// 327.220 us; speedup vs baseline: 1.5453x; 1.4220x over previous
//
#include <hip/hip_runtime.h>

#define BATCH 32768
#define NVEC  4096
#define EDIM  256
#define KNN   20

#define TS 128               // samples per gemm block
#define TC 128               // codes per gemm block
#define NCT (NVEC/TC)        // 32 code tiles
#define NST (BATCH/TS)       // 256 sample tiles
#define GGRID (NST*NCT)      // 8192 blocks
#define NKK 8                // K-steps of 32
#define MARGIN 2.0f          // > 2 * worst-case bf16 dot error (~0.8)
#define FINF   3.4e38f

typedef short          s16x8 __attribute__((ext_vector_type(8)));
typedef unsigned short u16x8 __attribute__((ext_vector_type(8)));
typedef float          f32x4 __attribute__((ext_vector_type(4)));

__device__ __forceinline__ unsigned short f2bf(float f) {
  unsigned int u = __float_as_uint(f);
  u += 0x7fffu + ((u >> 16) & 1u);   // RNE; inputs finite
  return (unsigned short)(u >> 16);
}

// monotone float->uint encoding: order-preserving over all finite floats
__device__ __forceinline__ unsigned int fenc(float f) {
  unsigned int u = __float_as_uint(f);
  return (u & 0x80000000u) ? ~u : (u | 0x80000000u);
}

// fp32 k-ascending dot — EXACT source pattern of the passing kernels
// (same compiler contraction => same rounding class as the reference).
__device__ __forceinline__ float dot_np(const float4* __restrict__ xq,
                                        const float4* __restrict__ wq) {
  float d = 0.f;
  for (int k = 0; k < EDIM / 4; k++) {
    float4 a4 = xq[k], b4 = wq[k];
    d += a4.x * b4.x;
    d += a4.y * b4.y;
    d += a4.z * b4.z;
    d += a4.w * b4.w;
  }
  return d;
}

__device__ __forceinline__ void gload16(const unsigned short* g, unsigned short* l) {
  __builtin_amdgcn_global_load_lds(
      (const __attribute__((address_space(1))) unsigned int*)g,
      (__attribute__((address_space(3))) unsigned int*)l, 16, 0, 0);
}

// fp32 row-major [R][256] -> bf16 fragment-order tiles.
// chunk c = ((rowtile*8 + kk)*8 + g): 1KB holding rows rowtile*128+g*16+lm,
// cols kk*32+lq*8 (8 bf16 per lane, lane = lq*16+lm). One wave per chunk.
__global__ __launch_bounds__(256)
void k_tilecvt(const float* __restrict__ src, unsigned short* __restrict__ dst) {
  const int lane = threadIdx.x & 63, wv = threadIdx.x >> 6;
  const int lm = lane & 15, lq = lane >> 4;
  const int c = blockIdx.x * 4 + wv;
  const int rt = c >> 6, kk = (c >> 3) & 7, g = c & 7;
  const int row = rt * 128 + g * 16 + lm;
  const float* p = src + (size_t)row * EDIM + kk * 32 + lq * 8;
  float4 a = ((const float4*)p)[0], b = ((const float4*)p)[1];
  u16x8 o;
  o[0] = f2bf(a.x); o[1] = f2bf(a.y); o[2] = f2bf(a.z); o[3] = f2bf(a.w);
  o[4] = f2bf(b.x); o[5] = f2bf(b.y); o[6] = f2bf(b.z); o[7] = f2bf(b.w);
  *(u16x8*)(dst + (size_t)c * 512 + lane * 8) = o;
}

// per-code weighted-window output table O[4096][256]; also inits flag
__global__ __launch_bounds__(256)
void k_code_out(const float* __restrict__ W, float* __restrict__ Otab,
                int* __restrict__ flag) {
  if (blockIdx.x == 0 && threadIdx.x == 0) *flag = 0;
  const int lane = threadIdx.x & 63;
  const int code = blockIdx.x * 4 + (threadIdx.x >> 6);
  float w = 0.f;
  if (lane < 41) {
    int d = lane - KNN;
    int idx = code + d;
    bool left  = (code - KNN) < 0;
    bool valid = (idx >= 0) && (idx < NVEC) && (!left || (d < KNN));
    w = valid ? expf(-0.5f * (float)(d * d)) : 0.f;
  }
  float ssum = w;
  #pragma unroll
  for (int off = 32; off >= 1; off >>= 1) ssum += __shfl_xor(ssum, off);
  float inv = 1.f / ssum;

  float4 acc = {0.f, 0.f, 0.f, 0.f};
  #pragma unroll
  for (int d = 0; d < 41; d++) {
    float wd = __shfl(w, d);
    int idx = code + d - KNN;
    idx = idx < 0 ? 0 : (idx >= NVEC ? NVEC - 1 : idx);
    float4 wr = *(const float4*)(W + (size_t)idx * EDIM + lane * 4);
    acc.x += wd * wr.x; acc.y += wd * wr.y;
    acc.z += wd * wr.z; acc.w += wd * wr.w;
  }
  acc.x *= inv; acc.y *= inv; acc.z *= inv; acc.w *= inv;
  *(float4*)(Otab + (size_t)code * EDIM + lane * 4) = acc;
}

// ---- tiled GEMM + per-tile argmin stats (m97 shape) ----
// 128x128 tile, 8 K-steps of 32. Both operands pre-tiled bf16 fragment-order;
// staged via global_load_lds (1KB contiguous per wave-instr), double-buffered
// 32KB LDS, one barrier per K-step. 4 blocks/CU co-resident hide the drains.
#define STAGE(kk_, buf_) { \
  gload16(wsrc + (kk_) * 4096 + (wv * 2    ) * 512 + lane * 8, wls + (buf_) * 4096 + (wv * 2    ) * 512); \
  gload16(wsrc + (kk_) * 4096 + (wv * 2 + 1) * 512 + lane * 8, wls + (buf_) * 4096 + (wv * 2 + 1) * 512); \
  gload16(xsrc + (kk_) * 4096 + (wv * 2    ) * 512 + lane * 8, xls + (buf_) * 4096 + (wv * 2    ) * 512); \
  gload16(xsrc + (kk_) * 4096 + (wv * 2 + 1) * 512 + lane * 8, xls + (buf_) * 4096 + (wv * 2 + 1) * 512); \
}

__global__ __launch_bounds__(256, 4)
void k_gemm(const float* __restrict__ x, const float* __restrict__ W,
            const unsigned short* __restrict__ Wt,
            const unsigned short* __restrict__ Xt,
            float4* __restrict__ part, int* __restrict__ flag) {
  __shared__ unsigned short wls[2 * 8 * 512];   // 16 KB (double-buffered W step)
  __shared__ unsigned short xls[2 * 8 * 512];   // 16 KB (double-buffered x step)

  const int t = threadIdx.x, lane = t & 63, wv = t >> 6;
  const int lm = lane & 15, lq = lane >> 4;
  const int wm = wv >> 1, wn = wv & 1;

  const int bid = blockIdx.x;
  const int swz = (bid & 7) * (GGRID / 8) + (bid >> 3);  // XCD-contiguous
  const int st = swz >> 5, ct = swz & 31;

  const unsigned short* wsrc = Wt + (size_t)ct * (NKK * 8 * 512);
  const unsigned short* xsrc = Xt + (size_t)st * (NKK * 8 * 512);

  f32x4 acc[4][4];
  #pragma unroll
  for (int i = 0; i < 4; i++)
    #pragma unroll
    for (int j = 0; j < 4; j++) acc[i][j] = (f32x4){0.f, 0.f, 0.f, 0.f};

  STAGE(0, 0)
  __syncthreads();   // vmcnt(0) drain: buf0 ready

  #pragma unroll
  for (int kk = 0; kk < NKK; kk++) {
    const int buf = kk & 1;
    if (kk < NKK - 1) STAGE(kk + 1, buf ^ 1)
    s16x8 av[4], bv[4];
    #pragma unroll
    for (int i = 0; i < 4; i++)
      av[i] = *(const s16x8*)(wls + buf * 4096 + (wn * 4 + i) * 512 + lane * 8);
    #pragma unroll
    for (int j = 0; j < 4; j++)
      bv[j] = *(const s16x8*)(xls + buf * 4096 + (wm * 4 + j) * 512 + lane * 8);
    #pragma unroll
    for (int i = 0; i < 4; i++)
      #pragma unroll
      for (int j = 0; j < 4; j++)
        acc[i][j] = __builtin_amdgcn_mfma_f32_16x16x32_bf16(av[i], bv[j], acc[i][j], 0, 0, 0);
    __syncthreads();   // next buf staged; this buf's reads done
  }

  // ---- layout self-check (one block, all wave quadrants, transpose-detecting) ----
  if (swz == 0) {
    float ex = dot_np((const float4*)(x + (size_t)(wm * 64 + lm) * EDIM),
                      (const float4*)(W + (size_t)(wn * 64 + lq * 4 + 1) * EDIM));
    if (fabsf(ex - acc[0][0][1]) > 2.0f) *flag = 1;
  }

  // ---- per-sample (m1,row,m2) over this wave's 64 codes, ascending row ----
  float m1a[4], m2a[4]; int r1a[4];
  #pragma unroll
  for (int j = 0; j < 4; j++) {
    float m1 = FINF, m2 = FINF; int r1 = 0;
    #pragma unroll
    for (int i = 0; i < 4; i++)
      #pragma unroll
      for (int r = 0; r < 4; r++) {
        float v = acc[i][j][r];
        m2 = fminf(m2, fmaxf(m1, v));
        bool lt = v < m1;
        r1 = lt ? (ct * TC + wn * 64 + i * 16 + lq * 4 + r) : r1;
        m1 = fminf(m1, v);
      }
    #pragma unroll
    for (int off = 16; off <= 32; off <<= 1) {
      float om1 = __shfl_xor(m1, off);
      float om2 = __shfl_xor(m2, off);
      int   or1 = __shfl_xor(r1, off);
      float nm2 = fminf(fminf(fmaxf(m1, om1), m2), om2);
      bool tk = (om1 < m1) || (om1 == m1 && or1 < r1);
      m1 = tk ? om1 : m1; r1 = tk ? or1 : r1; m2 = nm2;
    }
    m1a[j] = m1; m2a[j] = m2; r1a[j] = r1;
  }

  // merge wn halves via LDS (alias wls: all reads done), write partials
  float4* smrg = (float4*)wls;
  if (wn == 1 && lq == 0) {
    #pragma unroll
    for (int j = 0; j < 4; j++)
      smrg[wm * 64 + j * 16 + lm] =
          make_float4(m1a[j], m2a[j], __int_as_float(r1a[j]), 0.f);
  }
  __syncthreads();
  if (wn == 0 && lq == 0) {
    #pragma unroll
    for (int j = 0; j < 4; j++) {
      const int srow = wm * 64 + j * 16 + lm;
      float4 o = smrg[srow];
      float m1 = m1a[j], m2 = m2a[j]; int r1 = r1a[j];
      float nm2 = fminf(fminf(fmaxf(m1, o.x), m2), o.y);
      bool tk = (o.x < m1);   // wn1 rows always larger: tie keeps wn0 (smaller idx)
      m1 = tk ? o.x : m1;
      r1 = tk ? __float_as_int(o.z) : r1;
      // partials live in out[]: sample b's row, first 32 float4s (overwritten
      // by k_pick after it reads them)
      part[(size_t)(st * TS + srow) * (EDIM / 4) + ct] =
          make_float4(m1, nm2, __int_as_float(r1), 0.f);
    }
  }
}

// ---- per-sample reduce + exact-dot refine + output ----
__global__ __launch_bounds__(512)
void k_pick(const float* __restrict__ x, const float* __restrict__ W,
            const float* __restrict__ Otab, const int* __restrict__ flag,
            float* __restrict__ out) {
  const int lane = threadIdx.x & 63, wv = threadIdx.x >> 6;
  const int b = blockIdx.x * 8 + wv;
  const int c = lane & 31;

  // partials were written into this sample's own out row (first 512B)
  float4 p = ((const float4*)out)[(size_t)b * (EDIM / 4) + c];
  float m1 = p.x, m2 = p.y;
  int   r1 = __float_as_int(p.z);

  float gm = m1;
  #pragma unroll
  for (int off = 32; off >= 1; off >>= 1) gm = fminf(gm, __shfl_xor(gm, off));
  const float th = gm + MARGIN;

  const float4* xq = (const float4*)(x + (size_t)b * EDIM);
  unsigned long long best = 0xFFFFFFFFFFFFFFFFull;

  if (*flag == 0) {
    if (lane < 32 && m1 <= th) {
      float d = dot_np(xq, (const float4*)(W + (size_t)r1 * EDIM));
      best = ((unsigned long long)fenc(d) << 32) | (unsigned)r1;
    }
    // dirty contributors may hide extra near-min rows -> exact rescan (rare)
    unsigned long long db = __ballot(lane < 32 && m2 <= th);
    while (db) {
      int cc = __builtin_ctzll(db); db &= db - 1;
      const int base = cc * TC;
      #pragma unroll
      for (int tt = 0; tt < 2; tt++) {
        int row = base + lane * 2 + tt;
        float d = dot_np(xq, (const float4*)(W + (size_t)row * EDIM));
        unsigned long long key = ((unsigned long long)fenc(d) << 32) | (unsigned)row;
        if (key < best) best = key;
      }
    }
  } else {
    // layout-bad fallback: full np-order scan
    for (int n = lane; n < NVEC; n += 64) {
      float d = dot_np(xq, (const float4*)(W + (size_t)n * EDIM));
      unsigned long long key = ((unsigned long long)fenc(d) << 32) | (unsigned)n;
      if (key < best) best = key;
    }
  }

  #pragma unroll
  for (int off = 32; off >= 1; off >>= 1) {
    unsigned long long o = __shfl_xor(best, off);
    if (o < best) best = o;
  }
  const int id = (int)(unsigned int)(best & 0xFFFFFFFFull);
  float4 v = *(const float4*)(Otab + (size_t)id * EDIM + lane * 4);
  *(float4*)(out + (size_t)b * EDIM + lane * 4) = v;
}

extern "C" void kernel_launch(void* const* d_in, const int* in_sizes, int n_in,
                              void* d_out, int out_size, void* d_ws, size_t ws_size,
                              hipStream_t stream) {
  const float* x = (const float*)d_in[0];   // [32768,256] fp32
  const float* W = (const float*)d_in[1];   // [4096,256]  fp32
  float* out = (float*)d_out;

  char* ws = (char*)d_ws;
  unsigned short* Wt = (unsigned short*)ws;                 // 2 MB  (fragment-order bf16 W)
  unsigned short* Xt = (unsigned short*)(ws + (2u << 20));  // 16 MB (fragment-order bf16 x)
  float* Otab = (float*)(ws + (18u << 20));                 // 4 MB
  int* flag   = (int*)(ws + (22u << 20));                   // 4 B

  k_tilecvt<<<512, 256, 0, stream>>>(W, Wt);                // 2048 chunks
  k_tilecvt<<<4096, 256, 0, stream>>>(x, Xt);               // 16384 chunks
  k_code_out<<<1024, 256, 0, stream>>>(W, Otab, flag);
  k_gemm<<<GGRID, 256, 0, stream>>>(x, W, Wt, Xt, (float4*)out, flag);
  k_pick<<<BATCH / 8, 512, 0, stream>>>(x, W, Otab, flag, out);
}

// Round 5
// 266.175 us; speedup vs baseline: 1.8997x; 1.2293x over previous
//
#include <hip/hip_runtime.h>

#define BATCH 32768
#define NVEC  4096
#define EDIM  256
#define KNN   20

#define TS 128               // samples per gemm block
#define TC 128               // codes per gemm block
#define NCT (NVEC/TC)        // 32 code tiles
#define NST (BATCH/TS)       // 256 sample tiles
#define GGRID (NST*NCT)      // 8192 blocks
#define NKK 8                // K-steps of 32
#define MARGIN 2.0f          // > 2 * worst-case bf16 dot error (~0.8)
#define FINF   3.4e38f

typedef short          s16x8 __attribute__((ext_vector_type(8)));
typedef unsigned short u16x8 __attribute__((ext_vector_type(8)));
typedef float          f32x4 __attribute__((ext_vector_type(4)));

__device__ __forceinline__ unsigned short f2bf(float f) {
  unsigned int u = __float_as_uint(f);
  u += 0x7fffu + ((u >> 16) & 1u);   // RNE; inputs finite
  return (unsigned short)(u >> 16);
}

// monotone float->uint encoding: order-preserving over all finite floats
__device__ __forceinline__ unsigned int fenc(float f) {
  unsigned int u = __float_as_uint(f);
  return (u & 0x80000000u) ? ~u : (u | 0x80000000u);
}

// fp32 k-ascending dot — EXACT source pattern of the passing kernels
// (same compiler contraction => same rounding class as the reference).
__device__ __forceinline__ float dot_np(const float4* __restrict__ xq,
                                        const float4* __restrict__ wq) {
  float d = 0.f;
  for (int k = 0; k < EDIM / 4; k++) {
    float4 a4 = xq[k], b4 = wq[k];
    d += a4.x * b4.x;
    d += a4.y * b4.y;
    d += a4.z * b4.z;
    d += a4.w * b4.w;
  }
  return d;
}

__device__ __forceinline__ void gload16(const unsigned short* g, unsigned short* l) {
  __builtin_amdgcn_global_load_lds(
      (const __attribute__((address_space(1))) unsigned int*)g,
      (__attribute__((address_space(3))) unsigned int*)l, 16, 0, 0);
}

// fp32 row-major [R][256] -> bf16 fragment-order tiles.
// chunk c = ((rowtile*8 + kk)*8 + g): 1KB holding rows rowtile*128+g*16+lm,
// cols kk*32+lq*8 (8 bf16 per lane, lane = lq*16+lm). One wave per chunk.
__global__ __launch_bounds__(256)
void k_tilecvt(const float* __restrict__ src, unsigned short* __restrict__ dst) {
  const int lane = threadIdx.x & 63, wv = threadIdx.x >> 6;
  const int lm = lane & 15, lq = lane >> 4;
  const int c = blockIdx.x * 4 + wv;
  const int rt = c >> 6, kk = (c >> 3) & 7, g = c & 7;
  const int row = rt * 128 + g * 16 + lm;
  const float* p = src + (size_t)row * EDIM + kk * 32 + lq * 8;
  float4 a = ((const float4*)p)[0], b = ((const float4*)p)[1];
  u16x8 o;
  o[0] = f2bf(a.x); o[1] = f2bf(a.y); o[2] = f2bf(a.z); o[3] = f2bf(a.w);
  o[4] = f2bf(b.x); o[5] = f2bf(b.y); o[6] = f2bf(b.z); o[7] = f2bf(b.w);
  *(u16x8*)(dst + (size_t)c * 512 + lane * 8) = o;
}

// per-code weighted-window output table O[4096][256]; also inits flag
__global__ __launch_bounds__(256)
void k_code_out(const float* __restrict__ W, float* __restrict__ Otab,
                int* __restrict__ flag) {
  if (blockIdx.x == 0 && threadIdx.x == 0) *flag = 0;
  const int lane = threadIdx.x & 63;
  const int code = blockIdx.x * 4 + (threadIdx.x >> 6);
  float w = 0.f;
  if (lane < 41) {
    int d = lane - KNN;
    int idx = code + d;
    bool left  = (code - KNN) < 0;
    bool valid = (idx >= 0) && (idx < NVEC) && (!left || (d < KNN));
    w = valid ? expf(-0.5f * (float)(d * d)) : 0.f;
  }
  float ssum = w;
  #pragma unroll
  for (int off = 32; off >= 1; off >>= 1) ssum += __shfl_xor(ssum, off);
  float inv = 1.f / ssum;

  float4 acc = {0.f, 0.f, 0.f, 0.f};
  #pragma unroll
  for (int d = 0; d < 41; d++) {
    float wd = __shfl(w, d);
    int idx = code + d - KNN;
    idx = idx < 0 ? 0 : (idx >= NVEC ? NVEC - 1 : idx);
    float4 wr = *(const float4*)(W + (size_t)idx * EDIM + lane * 4);
    acc.x += wd * wr.x; acc.y += wd * wr.y;
    acc.z += wd * wr.z; acc.w += wd * wr.w;
  }
  acc.x *= inv; acc.y *= inv; acc.z *= inv; acc.w *= inv;
  *(float4*)(Otab + (size_t)code * EDIM + lane * 4) = acc;
}

// ---- tiled GEMM + per-tile argmin stats (m97 shape) ----
// 128x128 tile, 8 K-steps of 32. Both operands pre-tiled bf16 fragment-order;
// staged via global_load_lds (1KB contiguous per wave-instr), double-buffered
// 32KB LDS, one barrier per K-step. 4 blocks/CU co-resident hide the drains.
#define STAGE(kk_, buf_) { \
  gload16(wsrc + (kk_) * 4096 + (wv * 2    ) * 512 + lane * 8, wls + (buf_) * 4096 + (wv * 2    ) * 512); \
  gload16(wsrc + (kk_) * 4096 + (wv * 2 + 1) * 512 + lane * 8, wls + (buf_) * 4096 + (wv * 2 + 1) * 512); \
  gload16(xsrc + (kk_) * 4096 + (wv * 2    ) * 512 + lane * 8, xls + (buf_) * 4096 + (wv * 2    ) * 512); \
  gload16(xsrc + (kk_) * 4096 + (wv * 2 + 1) * 512 + lane * 8, xls + (buf_) * 4096 + (wv * 2 + 1) * 512); \
}

__global__ __launch_bounds__(256, 4)
void k_gemm(const float* __restrict__ x, const float* __restrict__ W,
            const unsigned short* __restrict__ Wt,
            const unsigned short* __restrict__ Xt,
            float4* __restrict__ part, int* __restrict__ flag) {
  __shared__ unsigned short wls[2 * 8 * 512];   // 16 KB (double-buffered W step)
  __shared__ unsigned short xls[2 * 8 * 512];   // 16 KB (double-buffered x step)

  const int t = threadIdx.x, lane = t & 63, wv = t >> 6;
  const int lm = lane & 15, lq = lane >> 4;
  const int wm = wv >> 1, wn = wv & 1;

  const int bid = blockIdx.x;
  const int swz = (bid & 7) * (GGRID / 8) + (bid >> 3);  // XCD-contiguous
  const int st = swz >> 5, ct = swz & 31;

  const unsigned short* wsrc = Wt + (size_t)ct * (NKK * 8 * 512);
  const unsigned short* xsrc = Xt + (size_t)st * (NKK * 8 * 512);

  f32x4 acc[4][4];
  #pragma unroll
  for (int i = 0; i < 4; i++)
    #pragma unroll
    for (int j = 0; j < 4; j++) acc[i][j] = (f32x4){0.f, 0.f, 0.f, 0.f};

  STAGE(0, 0)
  __syncthreads();   // vmcnt(0) drain: buf0 ready

  #pragma unroll
  for (int kk = 0; kk < NKK; kk++) {
    const int buf = kk & 1;
    if (kk < NKK - 1) STAGE(kk + 1, buf ^ 1)
    s16x8 av[4], bv[4];
    #pragma unroll
    for (int i = 0; i < 4; i++)
      av[i] = *(const s16x8*)(wls + buf * 4096 + (wn * 4 + i) * 512 + lane * 8);
    #pragma unroll
    for (int j = 0; j < 4; j++)
      bv[j] = *(const s16x8*)(xls + buf * 4096 + (wm * 4 + j) * 512 + lane * 8);
    #pragma unroll
    for (int i = 0; i < 4; i++)
      #pragma unroll
      for (int j = 0; j < 4; j++)
        acc[i][j] = __builtin_amdgcn_mfma_f32_16x16x32_bf16(av[i], bv[j], acc[i][j], 0, 0, 0);
    __syncthreads();   // next buf staged; this buf's reads done
  }

  // ---- layout self-check (one block, all wave quadrants, transpose-detecting) ----
  if (swz == 0) {
    float ex = dot_np((const float4*)(x + (size_t)(wm * 64 + lm) * EDIM),
                      (const float4*)(W + (size_t)(wn * 64 + lq * 4 + 1) * EDIM));
    if (fabsf(ex - acc[0][0][1]) > 2.0f) *flag = 1;
  }

  // ---- per-sample (m1,row,m2) over this wave's 64 codes, ascending row ----
  float m1a[4], m2a[4]; int r1a[4];
  #pragma unroll
  for (int j = 0; j < 4; j++) {
    float m1 = FINF, m2 = FINF; int r1 = 0;
    #pragma unroll
    for (int i = 0; i < 4; i++)
      #pragma unroll
      for (int r = 0; r < 4; r++) {
        float v = acc[i][j][r];
        m2 = fminf(m2, fmaxf(m1, v));
        bool lt = v < m1;
        r1 = lt ? (ct * TC + wn * 64 + i * 16 + lq * 4 + r) : r1;
        m1 = fminf(m1, v);
      }
    #pragma unroll
    for (int off = 16; off <= 32; off <<= 1) {
      float om1 = __shfl_xor(m1, off);
      float om2 = __shfl_xor(m2, off);
      int   or1 = __shfl_xor(r1, off);
      float nm2 = fminf(fminf(fmaxf(m1, om1), m2), om2);
      bool tk = (om1 < m1) || (om1 == m1 && or1 < r1);
      m1 = tk ? om1 : m1; r1 = tk ? or1 : r1; m2 = nm2;
    }
    m1a[j] = m1; m2a[j] = m2; r1a[j] = r1;
  }

  // merge wn halves via LDS (alias wls: all reads done), write partials
  float4* smrg = (float4*)wls;
  if (wn == 1 && lq == 0) {
    #pragma unroll
    for (int j = 0; j < 4; j++)
      smrg[wm * 64 + j * 16 + lm] =
          make_float4(m1a[j], m2a[j], __int_as_float(r1a[j]), 0.f);
  }
  __syncthreads();
  if (wn == 0 && lq == 0) {
    #pragma unroll
    for (int j = 0; j < 4; j++) {
      const int srow = wm * 64 + j * 16 + lm;
      float4 o = smrg[srow];
      float m1 = m1a[j], m2 = m2a[j]; int r1 = r1a[j];
      float nm2 = fminf(fminf(fmaxf(m1, o.x), m2), o.y);
      bool tk = (o.x < m1);   // wn1 rows always larger: tie keeps wn0 (smaller idx)
      m1 = tk ? o.x : m1;
      r1 = tk ? __float_as_int(o.z) : r1;
      // partials live in out[]: sample b's row, first 32 float4s (overwritten
      // by k_pick after it reads them)
      part[(size_t)(st * TS + srow) * (EDIM / 4) + ct] =
          make_float4(m1, nm2, __int_as_float(r1), 0.f);
    }
  }
}

// ---- per-sample reduce + (mostly dot-free) refine + output ----
// Singleton-candidate proof: true dot d(r) in [m(r)-E, m(r)+E], MARGIN >= 2E.
// The true argmin's contributor always has m1 <= gm+MARGIN. If exactly one
// contributor passes m1<=th and none passes m2<=th, that r1 IS the argmin:
// every other row r has m(r) > th so d(r) > gm+E >= d(r1). No exact dot needed.
__global__ __launch_bounds__(512)
void k_pick(const float* __restrict__ x, const float* __restrict__ W,
            const float* __restrict__ Otab, const int* __restrict__ flag,
            float* __restrict__ out) {
  const int lane = threadIdx.x & 63, wv = threadIdx.x >> 6;
  const int b = blockIdx.x * 8 + wv;
  const int c = lane & 31;

  // partials were written into this sample's own out row (first 512B)
  float4 p = ((const float4*)out)[(size_t)b * (EDIM / 4) + c];
  float m1 = p.x, m2 = p.y;
  int   r1 = __float_as_int(p.z);

  float gm = m1;
  #pragma unroll
  for (int off = 32; off >= 1; off >>= 1) gm = fminf(gm, __shfl_xor(gm, off));
  const float th = gm + MARGIN;

  const bool ok = (*flag == 0);
  unsigned long long bm1 = __ballot(lane < 32 && m1 <= th);
  unsigned long long bm2 = __ballot(lane < 32 && m2 <= th);

  int id;
  if (ok && __popcll(bm1) == 1 && bm2 == 0ull) {
    // easy path (~72%): singleton candidate, answer is its r1. No dots.
    id = __shfl(r1, (int)__builtin_ctzll(bm1));
  } else {
    const float4* xq = (const float4*)(x + (size_t)b * EDIM);
    unsigned long long best = 0xFFFFFFFFFFFFFFFFull;
    if (ok) {
      if (lane < 32 && m1 <= th) {
        float d = dot_np(xq, (const float4*)(W + (size_t)r1 * EDIM));
        best = ((unsigned long long)fenc(d) << 32) | (unsigned)r1;
      }
      // dirty contributors may hide extra near-min rows -> exact rescan (rare)
      unsigned long long db = bm2;
      while (db) {
        int cc = __builtin_ctzll(db); db &= db - 1;
        const int base = cc * TC;
        #pragma unroll
        for (int tt = 0; tt < 2; tt++) {
          int row = base + lane * 2 + tt;
          float d = dot_np(xq, (const float4*)(W + (size_t)row * EDIM));
          unsigned long long key = ((unsigned long long)fenc(d) << 32) | (unsigned)row;
          if (key < best) best = key;
        }
      }
    } else {
      // layout-bad fallback: full np-order scan
      for (int n = lane; n < NVEC; n += 64) {
        float d = dot_np(xq, (const float4*)(W + (size_t)n * EDIM));
        unsigned long long key = ((unsigned long long)fenc(d) << 32) | (unsigned)n;
        if (key < best) best = key;
      }
    }
    #pragma unroll
    for (int off = 32; off >= 1; off >>= 1) {
      unsigned long long o = __shfl_xor(best, off);
      if (o < best) best = o;
    }
    id = (int)(unsigned int)(best & 0xFFFFFFFFull);
  }

  float4 v = *(const float4*)(Otab + (size_t)id * EDIM + lane * 4);
  *(float4*)(out + (size_t)b * EDIM + lane * 4) = v;
}

extern "C" void kernel_launch(void* const* d_in, const int* in_sizes, int n_in,
                              void* d_out, int out_size, void* d_ws, size_t ws_size,
                              hipStream_t stream) {
  const float* x = (const float*)d_in[0];   // [32768,256] fp32
  const float* W = (const float*)d_in[1];   // [4096,256]  fp32
  float* out = (float*)d_out;

  char* ws = (char*)d_ws;
  unsigned short* Wt = (unsigned short*)ws;                 // 2 MB  (fragment-order bf16 W)
  unsigned short* Xt = (unsigned short*)(ws + (2u << 20));  // 16 MB (fragment-order bf16 x)
  float* Otab = (float*)(ws + (18u << 20));                 // 4 MB
  int* flag   = (int*)(ws + (22u << 20));                   // 4 B

  k_tilecvt<<<512, 256, 0, stream>>>(W, Wt);                // 2048 chunks
  k_tilecvt<<<4096, 256, 0, stream>>>(x, Xt);               // 16384 chunks
  k_code_out<<<1024, 256, 0, stream>>>(W, Otab, flag);
  k_gemm<<<GGRID, 256, 0, stream>>>(x, W, Wt, Xt, (float4*)out, flag);
  k_pick<<<BATCH / 8, 512, 0, stream>>>(x, W, Otab, flag, out);
}

// Round 6
// 253.513 us; speedup vs baseline: 1.9946x; 1.0499x over previous
//
#include <hip/hip_runtime.h>

#define BATCH 32768
#define NVEC  4096
#define EDIM  256
#define KNN   20

#define TS 128               // samples per gemm block
#define TC 128               // codes per gemm block
#define NCT (NVEC/TC)        // 32 code tiles
#define NST (BATCH/TS)       // 256 sample tiles
#define GGRID (NST*NCT)      // 8192 blocks
#define NKK 8                // K-steps of 32
#define MARGIN 2.0f          // > 2 * worst-case bf16 dot error (~0.8)
#define FINF   3.4e38f

typedef short          s16x8 __attribute__((ext_vector_type(8)));
typedef unsigned short u16x8 __attribute__((ext_vector_type(8)));
typedef float          f32x4 __attribute__((ext_vector_type(4)));

__device__ __forceinline__ unsigned short f2bf(float f) {
  unsigned int u = __float_as_uint(f);
  u += 0x7fffu + ((u >> 16) & 1u);   // RNE; inputs finite
  return (unsigned short)(u >> 16);
}

// monotone float->uint encoding: order-preserving over all finite floats
__device__ __forceinline__ unsigned int fenc(float f) {
  unsigned int u = __float_as_uint(f);
  return (u & 0x80000000u) ? ~u : (u | 0x80000000u);
}

// fp32 k-ascending dot — EXACT source pattern of the passing kernels
// (same compiler contraction => same rounding class as the reference).
__device__ __forceinline__ float dot_np(const float4* __restrict__ xq,
                                        const float4* __restrict__ wq) {
  float d = 0.f;
  for (int k = 0; k < EDIM / 4; k++) {
    float4 a4 = xq[k], b4 = wq[k];
    d += a4.x * b4.x;
    d += a4.y * b4.y;
    d += a4.z * b4.z;
    d += a4.w * b4.w;
  }
  return d;
}

__device__ __forceinline__ void gload16(const unsigned short* g, unsigned short* l) {
  __builtin_amdgcn_global_load_lds(
      (const __attribute__((address_space(1))) unsigned int*)g,
      (__attribute__((address_space(3))) unsigned int*)l, 16, 0, 0);
}

// streaming top-3 insert (values) + top-2 rows, branchless.
// strict '<': earlier-inserted row wins ties (set semantics safe either way).
#define INS3(v_, q_) { \
  float om1_ = m1, om2_ = m2; \
  m3 = fminf(m3, fmaxf(om2_, (v_))); \
  m2 = fminf(om2_, fmaxf(om1_, (v_))); \
  bool lt1_ = (v_) < om1_, lt2_ = (v_) < om2_; \
  r2 = lt1_ ? r1 : (lt2_ ? (q_) : r2); \
  r1 = lt1_ ? (q_) : r1; \
  m1 = fminf(om1_, (v_)); \
}

// fp32 row-major [R][256] -> bf16 fragment-order tiles.
// chunk c = ((rowtile*8 + kk)*8 + g): 1KB holding rows rowtile*128+g*16+lm,
// cols kk*32+lq*8 (8 bf16 per lane, lane = lq*16+lm). One wave per chunk.
__global__ __launch_bounds__(256)
void k_tilecvt(const float* __restrict__ src, unsigned short* __restrict__ dst) {
  const int lane = threadIdx.x & 63, wv = threadIdx.x >> 6;
  const int lm = lane & 15, lq = lane >> 4;
  const int c = blockIdx.x * 4 + wv;
  const int rt = c >> 6, kk = (c >> 3) & 7, g = c & 7;
  const int row = rt * 128 + g * 16 + lm;
  const float* p = src + (size_t)row * EDIM + kk * 32 + lq * 8;
  float4 a = ((const float4*)p)[0], b = ((const float4*)p)[1];
  u16x8 o;
  o[0] = f2bf(a.x); o[1] = f2bf(a.y); o[2] = f2bf(a.z); o[3] = f2bf(a.w);
  o[4] = f2bf(b.x); o[5] = f2bf(b.y); o[6] = f2bf(b.z); o[7] = f2bf(b.w);
  *(u16x8*)(dst + (size_t)c * 512 + lane * 8) = o;
}

// per-code weighted-window output table O[4096][256]; also inits flag
__global__ __launch_bounds__(256)
void k_code_out(const float* __restrict__ W, float* __restrict__ Otab,
                int* __restrict__ flag) {
  if (blockIdx.x == 0 && threadIdx.x == 0) *flag = 0;
  const int lane = threadIdx.x & 63;
  const int code = blockIdx.x * 4 + (threadIdx.x >> 6);
  float w = 0.f;
  if (lane < 41) {
    int d = lane - KNN;
    int idx = code + d;
    bool left  = (code - KNN) < 0;
    bool valid = (idx >= 0) && (idx < NVEC) && (!left || (d < KNN));
    w = valid ? expf(-0.5f * (float)(d * d)) : 0.f;
  }
  float ssum = w;
  #pragma unroll
  for (int off = 32; off >= 1; off >>= 1) ssum += __shfl_xor(ssum, off);
  float inv = 1.f / ssum;

  float4 acc = {0.f, 0.f, 0.f, 0.f};
  #pragma unroll
  for (int d = 0; d < 41; d++) {
    float wd = __shfl(w, d);
    int idx = code + d - KNN;
    idx = idx < 0 ? 0 : (idx >= NVEC ? NVEC - 1 : idx);
    float4 wr = *(const float4*)(W + (size_t)idx * EDIM + lane * 4);
    acc.x += wd * wr.x; acc.y += wd * wr.y;
    acc.z += wd * wr.z; acc.w += wd * wr.w;
  }
  acc.x *= inv; acc.y *= inv; acc.z *= inv; acc.w *= inv;
  *(float4*)(Otab + (size_t)code * EDIM + lane * 4) = acc;
}

// ---- tiled GEMM + per-tile top-3 argmin stats (m97 shape) ----
// 128x128 tile, 8 K-steps of 32. Both operands pre-tiled bf16 fragment-order;
// staged via global_load_lds (1KB contiguous per wave-instr), double-buffered
// 32KB LDS, one barrier per K-step. 4 blocks/CU co-resident hide the drains.
#define STAGE(kk_, buf_) { \
  gload16(wsrc + (kk_) * 4096 + (wv * 2    ) * 512 + lane * 8, wls + (buf_) * 4096 + (wv * 2    ) * 512); \
  gload16(wsrc + (kk_) * 4096 + (wv * 2 + 1) * 512 + lane * 8, wls + (buf_) * 4096 + (wv * 2 + 1) * 512); \
  gload16(xsrc + (kk_) * 4096 + (wv * 2    ) * 512 + lane * 8, xls + (buf_) * 4096 + (wv * 2    ) * 512); \
  gload16(xsrc + (kk_) * 4096 + (wv * 2 + 1) * 512 + lane * 8, xls + (buf_) * 4096 + (wv * 2 + 1) * 512); \
}

__global__ __launch_bounds__(256, 4)
void k_gemm(const float* __restrict__ x, const float* __restrict__ W,
            const unsigned short* __restrict__ Wt,
            const unsigned short* __restrict__ Xt,
            float4* __restrict__ part, int* __restrict__ flag) {
  __shared__ unsigned short wls[2 * 8 * 512];   // 16 KB (double-buffered W step)
  __shared__ unsigned short xls[2 * 8 * 512];   // 16 KB (double-buffered x step)

  const int t = threadIdx.x, lane = t & 63, wv = t >> 6;
  const int lm = lane & 15, lq = lane >> 4;
  const int wm = wv >> 1, wn = wv & 1;

  const int bid = blockIdx.x;
  const int swz = (bid & 7) * (GGRID / 8) + (bid >> 3);  // XCD-contiguous
  const int st = swz >> 5, ct = swz & 31;

  const unsigned short* wsrc = Wt + (size_t)ct * (NKK * 8 * 512);
  const unsigned short* xsrc = Xt + (size_t)st * (NKK * 8 * 512);

  f32x4 acc[4][4];
  #pragma unroll
  for (int i = 0; i < 4; i++)
    #pragma unroll
    for (int j = 0; j < 4; j++) acc[i][j] = (f32x4){0.f, 0.f, 0.f, 0.f};

  STAGE(0, 0)
  __syncthreads();   // vmcnt(0) drain: buf0 ready

  #pragma unroll
  for (int kk = 0; kk < NKK; kk++) {
    const int buf = kk & 1;
    if (kk < NKK - 1) STAGE(kk + 1, buf ^ 1)
    s16x8 av[4], bv[4];
    #pragma unroll
    for (int i = 0; i < 4; i++)
      av[i] = *(const s16x8*)(wls + buf * 4096 + (wn * 4 + i) * 512 + lane * 8);
    #pragma unroll
    for (int j = 0; j < 4; j++)
      bv[j] = *(const s16x8*)(xls + buf * 4096 + (wm * 4 + j) * 512 + lane * 8);
    #pragma unroll
    for (int i = 0; i < 4; i++)
      #pragma unroll
      for (int j = 0; j < 4; j++)
        acc[i][j] = __builtin_amdgcn_mfma_f32_16x16x32_bf16(av[i], bv[j], acc[i][j], 0, 0, 0);
    __syncthreads();   // next buf staged; this buf's reads done
  }

  // ---- layout self-check (one block, all wave quadrants, transpose-detecting) ----
  if (swz == 0) {
    float ex = dot_np((const float4*)(x + (size_t)(wm * 64 + lm) * EDIM),
                      (const float4*)(W + (size_t)(wn * 64 + lq * 4 + 1) * EDIM));
    if (fabsf(ex - acc[0][0][1]) > 2.0f) *flag = 1;
  }

  // ---- per-sample (m1,r1 | m2,r2 | m3) over this wave's 64 codes ----
  float m1a[4], m2a[4], m3a[4]; int r1a[4], r2a[4];
  #pragma unroll
  for (int j = 0; j < 4; j++) {
    float m1 = FINF, m2 = FINF, m3 = FINF; int r1 = 0, r2 = 0;
    #pragma unroll
    for (int i = 0; i < 4; i++)
      #pragma unroll
      for (int r = 0; r < 4; r++) {
        float v = acc[i][j][r];
        int rowc = ct * TC + wn * 64 + i * 16 + lq * 4 + r;  // ascending per lane
        INS3(v, rowc)
      }
    // reduce over the 4 lq lanes of this lm (lane, ^16, ^32, ^48)
    #pragma unroll
    for (int off = 16; off <= 32; off <<= 1) {
      float o1 = __shfl_xor(m1, off);
      float o2 = __shfl_xor(m2, off);
      float o3 = __shfl_xor(m3, off);
      int   q1 = __shfl_xor(r1, off);
      int   q2 = __shfl_xor(r2, off);
      INS3(o1, q1)
      INS3(o2, q2)
      m3 = fminf(m3, fmaxf(m2, o3));   // o3 can never reach top-2
    }
    m1a[j] = m1; m2a[j] = m2; m3a[j] = m3; r1a[j] = r1; r2a[j] = r2;
  }

  // merge wn halves via LDS (alias wls: all reads done), write partials
  float4* smrg = (float4*)wls;
  if (wn == 1 && lq == 0) {
    #pragma unroll
    for (int j = 0; j < 4; j++)
      smrg[wm * 64 + j * 16 + lm] =
          make_float4(m1a[j], m2a[j], m3a[j],
                      __int_as_float(r1a[j] | (r2a[j] << 12)));
  }
  __syncthreads();
  if (wn == 0 && lq == 0) {
    #pragma unroll
    for (int j = 0; j < 4; j++) {
      const int srow = wm * 64 + j * 16 + lm;
      float4 o = smrg[srow];
      float m1 = m1a[j], m2 = m2a[j], m3 = m3a[j];
      int r1 = r1a[j], r2 = r2a[j];
      int op = __float_as_int(o.w);
      int q1 = op & 0xFFF, q2 = (op >> 12) & 0xFFF;
      INS3(o.x, q1)       // wn1 rows larger: strict '<' keeps wn0 on ties
      INS3(o.y, q2)
      m3 = fminf(m3, fmaxf(m2, o.z));
      // partials live in out[]: sample b's row, first 32 float4s (overwritten
      // by k_pick after it reads them)
      part[(size_t)(st * TS + srow) * (EDIM / 4) + ct] =
          make_float4(m1, m2, m3, __int_as_float(r1 | (r2 << 12)));
    }
  }
}

// ---- per-sample reduce + (mostly dot-free) refine + output ----
// Screen error E: |screen(r) - d(r)| <= E, MARGIN >= 2E. The true argmin r*
// has screen(r*) <= gm+MARGIN. Candidate set {r : screen(r) <= th} is fully
// enumerated by {r1(c), r2(c)} plus full rescans of tiles with m3 <= th
// (3+ near-min rows in one tile: ~never). Singleton path: if exactly one
// contributor has m1<=th and none has m2<=th, that r1 IS the argmin (any
// other row r has screen(r) > th so d(r) > gm+E >= d(r1)). No dots needed.
__global__ __launch_bounds__(512)
void k_pick(const float* __restrict__ x, const float* __restrict__ W,
            const float* __restrict__ Otab, const int* __restrict__ flag,
            float* __restrict__ out) {
  const int lane = threadIdx.x & 63, wv = threadIdx.x >> 6;
  const int b = blockIdx.x * 8 + wv;
  const int c = lane & 31;   // both 32-lane halves hold the same contributor

  // partials were written into this sample's own out row (first 512B)
  float4 p = ((const float4*)out)[(size_t)b * (EDIM / 4) + c];
  float m1 = p.x, m2 = p.y, m3 = p.z;
  int rows = __float_as_int(p.w);
  int r1 = rows & 0xFFF, r2 = (rows >> 12) & 0xFFF;

  float gm = m1;
  #pragma unroll
  for (int off = 32; off >= 1; off >>= 1) gm = fminf(gm, __shfl_xor(gm, off));
  const float th = gm + MARGIN;

  const bool ok = (*flag == 0);
  unsigned long long bm1 = __ballot(lane < 32 && m1 <= th);
  unsigned long long bm2 = __ballot(lane < 32 && m2 <= th);

  int id;
  if (ok && __popcll(bm1) == 1 && bm2 == 0ull) {
    // easy path (~72%): singleton candidate, answer is its r1. No dots.
    id = __shfl(r1, (int)__builtin_ctzll(bm1));
  } else {
    const float4* xq = (const float4*)(x + (size_t)b * EDIM);
    unsigned long long best = 0xFFFFFFFFFFFFFFFFull;
    if (ok) {
      // one candidate dot per lane: lower half takes r1, upper half takes r2
      const int  myr = (lane < 32) ? r1 : r2;
      const bool mym = (lane < 32) ? (m1 <= th) : (m2 <= th);
      if (mym) {
        float d = dot_np(xq, (const float4*)(W + (size_t)myr * EDIM));
        best = ((unsigned long long)fenc(d) << 32) | (unsigned)myr;
      }
      // tiles with 3+ near-min rows -> exact rescan (~never)
      unsigned long long db = __ballot(lane < 32 && m3 <= th);
      while (db) {
        int cc = __builtin_ctzll(db); db &= db - 1;
        const int base = cc * TC;
        #pragma unroll
        for (int tt = 0; tt < 2; tt++) {
          int row = base + lane * 2 + tt;
          float d = dot_np(xq, (const float4*)(W + (size_t)row * EDIM));
          unsigned long long key = ((unsigned long long)fenc(d) << 32) | (unsigned)row;
          if (key < best) best = key;
        }
      }
    } else {
      // layout-bad fallback: full np-order scan
      for (int n = lane; n < NVEC; n += 64) {
        float d = dot_np(xq, (const float4*)(W + (size_t)n * EDIM));
        unsigned long long key = ((unsigned long long)fenc(d) << 32) | (unsigned)n;
        if (key < best) best = key;
      }
    }
    #pragma unroll
    for (int off = 32; off >= 1; off >>= 1) {
      unsigned long long o = __shfl_xor(best, off);
      if (o < best) best = o;
    }
    id = (int)(unsigned int)(best & 0xFFFFFFFFull);
  }

  float4 v = *(const float4*)(Otab + (size_t)id * EDIM + lane * 4);
  *(float4*)(out + (size_t)b * EDIM + lane * 4) = v;
}

extern "C" void kernel_launch(void* const* d_in, const int* in_sizes, int n_in,
                              void* d_out, int out_size, void* d_ws, size_t ws_size,
                              hipStream_t stream) {
  const float* x = (const float*)d_in[0];   // [32768,256] fp32
  const float* W = (const float*)d_in[1];   // [4096,256]  fp32
  float* out = (float*)d_out;

  char* ws = (char*)d_ws;
  unsigned short* Wt = (unsigned short*)ws;                 // 2 MB  (fragment-order bf16 W)
  unsigned short* Xt = (unsigned short*)(ws + (2u << 20));  // 16 MB (fragment-order bf16 x)
  float* Otab = (float*)(ws + (18u << 20));                 // 4 MB
  int* flag   = (int*)(ws + (22u << 20));                   // 4 B

  k_tilecvt<<<512, 256, 0, stream>>>(W, Wt);                // 2048 chunks
  k_tilecvt<<<4096, 256, 0, stream>>>(x, Xt);               // 16384 chunks
  k_code_out<<<1024, 256, 0, stream>>>(W, Otab, flag);
  k_gemm<<<GGRID, 256, 0, stream>>>(x, W, Wt, Xt, (float4*)out, flag);
  k_pick<<<BATCH / 8, 512, 0, stream>>>(x, W, Otab, flag, out);
}